// Round 11
// baseline (111.268 us; speedup 1.0000x reference)
//
#include <hip/hip_runtime.h>
#include <hip/hip_bf16.h>
#include <cstdint>
#include <cstddef>

typedef __bf16 bf16;
typedef bf16 bf16x8 __attribute__((ext_vector_type(8)));
typedef bf16 bf16x4 __attribute__((ext_vector_type(4)));
typedef bf16 bf16x2 __attribute__((ext_vector_type(2)));
typedef float f32x4 __attribute__((ext_vector_type(4)));
typedef float f32x16 __attribute__((ext_vector_type(16)));

#define MFMA16(A, B, Cc) __builtin_amdgcn_mfma_f32_16x16x32_bf16((A), (B), (Cc), 0, 0, 0)
#define MFMA32(A, B, Cc) __builtin_amdgcn_mfma_f32_32x32x16_bf16((A), (B), (Cc), 0, 0, 0)
#define GLD16(g, l)                                                          \
  __builtin_amdgcn_global_load_lds(                                          \
      (const __attribute__((address_space(1))) void*)(g),                    \
      (__attribute__((address_space(3))) void*)(l), 16, 0, 0)

// raw exp2 (Q pre-scaled by log2e at k_proj store -> exp(Q.K) == exp2(z))
#if __has_builtin(__builtin_amdgcn_exp2f)
#define EXP2(x) __builtin_amdgcn_exp2f(x)
#else
#define EXP2(x) exp2f(x)
#endif

static constexpr int L   = 4096;  // H*W
static constexpr int CH  = 256;   // channels
static constexpr int NH  = 4;     // heads

// workspace layout (bytes), all 16B aligned
static constexpr size_t OFF_WALL = 0;         // 768*256 bf16
static constexpr size_t OFF_WMB  = 393216;    // 256*256 bf16
static constexpr size_t OFF_BALL = 524288;    // 768 f32 (+pad)
static constexpr size_t OFF_XT   = 528384;    // [B][L][C] bf16 (4MB) -- Rp0 aliases after k_proj
static constexpr size_t OFF_QT   = 4722688;   // [B][H][L][64] bf16 (4MB, pre-scaled by log2e)
static constexpr size_t OFF_KT   = 8916992;   // [B][H][L][64] bf16 (4MB)
static constexpr size_t OFF_VD   = 13111296;  // [B][H][64][L] bf16 (4MB, j-bits-2/3-swapped)
static constexpr size_t OFF_RP1  = 17305600;  // partials js=1.. (4MB each)
static constexpr size_t RPSZ     = 4194304;   // bytes per partial
static constexpr size_t RPE      = 2097152;   // elements per partial
static constexpr size_t OFF_DP4  = OFF_RP1 + 3 * RPSZ;   // JS=4 denoms
static constexpr size_t NEED4    = OFF_DP4 + 4 * 131072; // 30412800 (proven available)
static constexpr size_t OFF_DP2  = OFF_RP1 + 1 * RPSZ;   // JS=2 denoms

// ---------------- kernel 0: weight/bias convert (vectorized) + x transpose ---
__global__ __launch_bounds__(256) void k_prep(
    const float* __restrict__ Wq, const float* __restrict__ Wk,
    const float* __restrict__ Wv, const float* __restrict__ bq,
    const float* __restrict__ bk, const float* __restrict__ bv,
    const float* __restrict__ Wm, const float* __restrict__ x,
    bf16* __restrict__ Wall, float* __restrict__ ball,
    bf16* __restrict__ Wmb, bf16* __restrict__ xT) {
  __shared__ float t[32][33];
  const int bid = blockIdx.x;
  const int tid = threadIdx.x;
  if (bid < 256) {
    // 262144 weight elems, 4 per thread, float4 -> bf16x4
    const int id4 = (bid * 256 + tid) * 4;
    const float* src;
    bf16* dst;
    if (id4 < 65536)       { src = Wq + id4;          dst = Wall + id4; }
    else if (id4 < 131072) { src = Wk + id4 - 65536;  dst = Wall + id4; }
    else if (id4 < 196608) { src = Wv + id4 - 131072; dst = Wall + id4; }
    else                   { src = Wm + id4 - 196608; dst = Wmb + id4 - 196608; }
    f32x4 v = *(const f32x4*)src;
    bf16x4 o;
    o[0] = (bf16)v[0]; o[1] = (bf16)v[1]; o[2] = (bf16)v[2]; o[3] = (bf16)v[3];
    *(bf16x4*)dst = o;
  } else if (bid == 256) {
    // all 768 bias entries: each of the 256 threads copies 3
    ball[tid]       = bq[tid];
    ball[256 + tid] = bk[tid];
    ball[512 + tid] = bv[tid];
  } else {
    const int id = bid - 257;           // 0..2047
    const int b = id >> 10;
    const int c0 = ((id >> 7) & 7) * 32;
    const int l0 = (id & 127) * 32;
    const int tx = tid & 31, ty = tid >> 5;
    #pragma unroll
    for (int i = 0; i < 4; ++i) {
      int c = c0 + ty + 8 * i;
      t[ty + 8 * i][tx] = x[((size_t)b * CH + c) * L + l0 + tx];
    }
    __syncthreads();
    #pragma unroll
    for (int i = 0; i < 4; ++i) {
      int l = l0 + ty + 8 * i;
      xT[((size_t)b * L + l) * CH + c0 + tx] = (bf16)t[tx][ty + 8 * i];
    }
  }
}

// ---------------- kernel 2: fused QKV projection + L2 norm ----------------
// N=32 per wave (grid 768 blocks ~ 3/CU). V stored with j-bits 2<->3 swapped
// along L (so k_attn's PV A-frag is a straight register pack). Q additionally
// scaled by log2(e) so k_attn can use raw exp2.
__global__ __launch_bounds__(256) void k_proj(
    const bf16* __restrict__ Wall, const float* __restrict__ ball,
    const bf16* __restrict__ xT, bf16* __restrict__ Qt,
    bf16* __restrict__ Kt, bf16* __restrict__ Vd) {
  const int b = blockIdx.z, strip = blockIdx.y, lt = blockIdx.x;
  const int w = threadIdx.x >> 6;
  const int lane = threadIdx.x & 63;
  const int lo = lane & 15, g = lane >> 4;
  const int l0 = lt * 128 + w * 32;

  const bf16* wbase = Wall + (size_t)strip * 64 * CH;
  const bf16* xbase = xT + (size_t)b * L * CH;

  f32x4 acc[4][2];
  #pragma unroll
  for (int m = 0; m < 4; ++m)
    #pragma unroll
    for (int n = 0; n < 2; ++n) acc[m][n] = (f32x4){0.f, 0.f, 0.f, 0.f};

  #pragma unroll
  for (int kc = 0; kc < 8; ++kc) {
    bf16x8 aw[4], bx[2];
    #pragma unroll
    for (int m = 0; m < 4; ++m)
      aw[m] = *(const bf16x8*)(wbase + (size_t)(16 * m + lo) * CH + kc * 32 + g * 8);
    #pragma unroll
    for (int n = 0; n < 2; ++n)
      bx[n] = *(const bf16x8*)(xbase + (size_t)(l0 + 16 * n + lo) * CH + kc * 32 + g * 8);
    #pragma unroll
    for (int m = 0; m < 4; ++m)
      #pragma unroll
      for (int n = 0; n < 2; ++n) acc[m][n] = MFMA16(aw[m], bx[n], acc[m][n]);
  }

  #pragma unroll
  for (int m = 0; m < 4; ++m)
    #pragma unroll
    for (int r = 0; r < 4; ++r) {
      float bias = ball[strip * 64 + 16 * m + 4 * g + r];
      #pragma unroll
      for (int n = 0; n < 2; ++n) acc[m][n][r] += bias;
    }

  if (strip < 8) {
    #pragma unroll
    for (int n = 0; n < 2; ++n) {
      float ss = 0.f;
      #pragma unroll
      for (int m = 0; m < 4; ++m)
        #pragma unroll
        for (int r = 0; r < 4; ++r) ss += acc[m][n][r] * acc[m][n][r];
      ss += __shfl_xor(ss, 16);
      ss += __shfl_xor(ss, 32);
      float sc = 1.f / fmaxf(sqrtf(ss), 1e-6f);
      if (strip < 4) sc *= 1.44269504f;  // fold log2(e) into Q
      #pragma unroll
      for (int m = 0; m < 4; ++m)
        #pragma unroll
        for (int r = 0; r < 4; ++r) acc[m][n][r] *= sc;
    }
    bf16* dst = (strip < 4) ? Qt : Kt;
    const int h = strip & 3;
    #pragma unroll
    for (int n = 0; n < 2; ++n) {
      const int l = l0 + 16 * n + lo;
      #pragma unroll
      for (int m = 0; m < 4; ++m) {
        size_t base = ((size_t)(b * NH + h) * L + l) * 64 + 16 * m + 4 * g;
        bf16x2 v01, v23;
        v01[0] = (bf16)acc[m][n][0]; v01[1] = (bf16)acc[m][n][1];
        v23[0] = (bf16)acc[m][n][2]; v23[1] = (bf16)acc[m][n][3];
        *(bf16x2*)(dst + base)     = v01;
        *(bf16x2*)(dst + base + 2) = v23;
      }
    }
  } else {
    const int h = strip - 8;
    const int lop = (lo & 3) | ((lo & 4) << 1) | ((lo & 8) >> 1);  // swap bits 2,3
    #pragma unroll
    for (int m = 0; m < 4; ++m)
      #pragma unroll
      for (int r = 0; r < 4; ++r) {
        const int d = 16 * m + 4 * g + r;
        #pragma unroll
        for (int n = 0; n < 2; ++n) {
          const int l = l0 + 16 * n + lop;
          Vd[((size_t)(b * NH + h) * 64 + d) * L + l] = (bf16)acc[m][n][r];
        }
      }
  }
}

// ---------------- kernel 3: attention (32x32 MFMA, in-register P) -----------
// R4-exact structure (measured 44.16us / VGPR 124; setprio REVERTED -- R9
// showed it regresses lockstep loops). 4 waves x 64 q. K/V LDS-staged
// (global_load_lds, 3-buffer ring, 2 tiles in flight, counted vmcnt).
// Swapped QK (A=K, B=Q); V j-axis bit-2/3-swapped so PV A-frags are
// register packs of exp2(QK) output (Q pre-scaled by log2e).

#define STAGE(kdst, vdst, j0)                                                  \
  {                                                                            \
    const char* gk0 = kbase + (size_t)((j0) + sr) * 128 + scS;                 \
    const char* gk1 = kbase + (size_t)((j0) + 32 + sr) * 128 + scS;            \
    const char* gv0 = vbase + (size_t)sr * 8192 + (size_t)(j0) * 2 + scS;      \
    const char* gv1 = vbase + (size_t)(32 + sr) * 8192 + (size_t)(j0) * 2 + scS; \
    GLD16(gk0, (kdst) + tid * 16);                                             \
    GLD16(gk1, (kdst) + 4096 + tid * 16);                                      \
    GLD16(gv0, (vdst) + tid * 16);                                             \
    GLD16(gv1, (vdst) + 4096 + tid * 16);                                      \
  }

#define COMPUTE(kb_, vb_)                                                      \
  {                                                                            \
    const char* kb = (kb_);                                                    \
    const char* vb = (vb_);                                                    \
    _Pragma("unroll") for (int jb = 0; jb < 2; ++jb) {                         \
      bf16x8 kf[4], vf[2][2];                                                  \
      _Pragma("unroll") for (int f = 0; f < 4; ++f)                            \
        kf[f] = *(const bf16x8*)(kb + (32 * jb + ln) * 128 +                   \
                                 ((32 * f + 16 * hi) ^ sw));                   \
      _Pragma("unroll") for (int dvb = 0; dvb < 2; ++dvb)                      \
        _Pragma("unroll") for (int c = 0; c < 2; ++c)                          \
          vf[dvb][c] = *(const bf16x8*)(vb + (32 * dvb + ln) * 128 +           \
                                        ((64 * jb + 32 * c + 16 * hi) ^ sw));  \
      _Pragma("unroll") for (int qb = 0; qb < 2; ++qb) {                       \
        f32x16 z;                                                              \
        _Pragma("unroll") for (int r = 0; r < 16; ++r) z[r] = 0.f;             \
        _Pragma("unroll") for (int f = 0; f < 4; ++f)                          \
          z = MFMA32(kf[f], qf[qb][f], z);                                     \
        float p[16];                                                           \
        _Pragma("unroll") for (int r = 0; r < 16; ++r) p[r] = EXP2(z[r]);      \
        float t0 = (p[0] + p[1]) + (p[2] + p[3]);                              \
        float t1 = (p[4] + p[5]) + (p[6] + p[7]);                              \
        float t2 = (p[8] + p[9]) + (p[10] + p[11]);                            \
        float t3 = (p[12] + p[13]) + (p[14] + p[15]);                          \
        den[qb] += (t0 + t1) + (t2 + t3);                                      \
        bf16x8 pf0, pf1;                                                       \
        _Pragma("unroll") for (int e = 0; e < 8; ++e) {                        \
          pf0[e] = (bf16)p[e];                                                 \
          pf1[e] = (bf16)p[8 + e];                                             \
        }                                                                      \
        _Pragma("unroll") for (int dvb = 0; dvb < 2; ++dvb) {                  \
          racc[qb][dvb] = MFMA32(pf0, vf[dvb][0], racc[qb][dvb]);              \
          racc[qb][dvb] = MFMA32(pf1, vf[dvb][1], racc[qb][dvb]);              \
        }                                                                      \
      }                                                                        \
    }                                                                          \
  }

template <int JS>
__global__ __launch_bounds__(256) void k_attn(
    const bf16* __restrict__ Qt, const bf16* __restrict__ Kt,
    const bf16* __restrict__ Vd, bf16* __restrict__ Rp0,
    bf16* __restrict__ Rlin, float* __restrict__ Dbase) {
  const int id = blockIdx.x;
  const int bh = id & 7;              // per-head XCD affinity
  const int qt = (id >> 3) & 15;
  const int js = id >> 7;
  const int tid = threadIdx.x;
  const int w = tid >> 6;
  const int lane = tid & 63;
  const int ln = lane & 31, hi = lane >> 5;
  const int sw = (ln & 7) << 4;
  const int i0 = qt * 256 + w * 64;

  __shared__ __align__(16) char kbuf[3][8192];
  __shared__ __align__(16) char vbuf[3][8192];

  const char* kbase = (const char*)(Kt + (size_t)bh * L * 64);
  const char* vbase = (const char*)(Vd + (size_t)bh * 64 * L);

  const int sr = tid >> 3;
  const int sc = (tid & 7) * 16;
  const int scS = sc ^ ((sr & 7) << 4);

  // Q B-frags: qf[qb][f] = Q[i0+32qb+ln][16f+8hi .. +7]
  const bf16* qbp = Qt + ((size_t)bh * L + i0) * 64;
  bf16x8 qf[2][4];
  #pragma unroll
  for (int qb = 0; qb < 2; ++qb)
    #pragma unroll
    for (int f = 0; f < 4; ++f)
      qf[qb][f] = *(const bf16x8*)(qbp + (size_t)(32 * qb + ln) * 64 + 16 * f + 8 * hi);

  f32x16 racc[2][2];
  #pragma unroll
  for (int qb = 0; qb < 2; ++qb)
    #pragma unroll
    for (int dvb = 0; dvb < 2; ++dvb)
      #pragma unroll
      for (int r = 0; r < 16; ++r) racc[qb][dvb][r] = 0.f;
  float den[2] = {0.f, 0.f};

  const int jbeg = js * (L / JS);
  const int nt = (L / JS) / 64;

  // 2-deep prefetch into 3-buffer ring; counted vmcnt keeps 4 loads in
  // flight across barriers (no vmcnt(0) drain until the tail).
  STAGE(kbuf[0], vbuf[0], jbeg)
  STAGE(kbuf[1], vbuf[1], jbeg + 64)
  asm volatile("s_waitcnt vmcnt(4)" ::: "memory");
  __builtin_amdgcn_s_barrier();

  int bc = 0, bs = 2;
  for (int it = 0; it < nt; ++it) {
    if (it + 2 < nt) STAGE(kbuf[bs], vbuf[bs], jbeg + (it + 2) * 64)
    COMPUTE(kbuf[bc], vbuf[bc])
    if (it + 1 < nt) {
      if (it + 2 < nt)
        asm volatile("s_waitcnt vmcnt(4)" ::: "memory");
      else
        asm volatile("s_waitcnt vmcnt(0)" ::: "memory");
      __builtin_amdgcn_s_barrier();
    }
    bc = (bc == 2) ? 0 : bc + 1;
    bs = (bs == 2) ? 0 : bs + 1;
  }

  // full denominator: lane-local sum covers its hi-half of j; add the other.
  #pragma unroll
  for (int qb = 0; qb < 2; ++qb) den[qb] += __shfl_xor(den[qb], 32);

  bf16* rp = (js == 0) ? Rp0 : (Rlin + (size_t)(js - 1) * RPE);
  float* dp = Dbase + (size_t)js * 32768;

  if (hi == 0) {
    #pragma unroll
    for (int qb = 0; qb < 2; ++qb)
      dp[(size_t)bh * L + i0 + 32 * qb + ln] = den[qb];
  }
  #pragma unroll
  for (int qb = 0; qb < 2; ++qb)
    #pragma unroll
    for (int dvb = 0; dvb < 2; ++dvb)
      #pragma unroll
      for (int r = 0; r < 16; ++r) {
        const int q = 32 * qb + (r & 3) + 8 * (r >> 2) + 4 * hi;
        rp[((size_t)bh * L + i0 + q) * 64 + 32 * dvb + ln] = (bf16)racc[qb][dvb][r];
      }
}

// ---------------- kernel 4: output projection + combine + bias + residual ----
// R4-proven config: 32 l's per block, grid (128,2). B-frags built on the fly
// from the JS unnormalized partials + denominators.
template <int JS>
__global__ __launch_bounds__(256) void k_out(
    const bf16* __restrict__ Wmb, const bf16* __restrict__ R0,
    const bf16* __restrict__ Rlin, const float* __restrict__ Dbase,
    const float* __restrict__ x, const float* __restrict__ bm,
    float* __restrict__ out) {
  const int b = blockIdx.y, lt = blockIdx.x;  // 128 l-tiles of 32
  const int w = threadIdx.x >> 6;
  const int lane = threadIdx.x & 63;
  const int lo = lane & 15, g = lane >> 4;
  const int o0 = w * 64, l0 = lt * 32;

  float invd[2][4];
  #pragma unroll
  for (int n = 0; n < 2; ++n) {
    const int l = l0 + 16 * n + lo;
    #pragma unroll
    for (int h = 0; h < 4; ++h) {
      const size_t di = (size_t)(b * NH + h) * L + l;
      float dd = 0.f;
      #pragma unroll
      for (int js = 0; js < JS; ++js) dd += Dbase[(size_t)js * 32768 + di];
      invd[n][h] = 1.0f / dd;
    }
  }

  f32x4 acc[4][2];
  #pragma unroll
  for (int m = 0; m < 4; ++m)
    #pragma unroll
    for (int n = 0; n < 2; ++n) acc[m][n] = (f32x4){0.f, 0.f, 0.f, 0.f};

  #pragma unroll
  for (int kc = 0; kc < 8; ++kc) {
    bf16x8 aw[4], bx[2];
    #pragma unroll
    for (int m = 0; m < 4; ++m)
      aw[m] = *(const bf16x8*)(Wmb + (size_t)(o0 + 16 * m + lo) * CH + kc * 32 + g * 8);
    const int h = kc >> 1;
    #pragma unroll
    for (int n = 0; n < 2; ++n) {
      const size_t base = ((size_t)(b * NH + h) * L + (l0 + 16 * n + lo)) * 64 +
                          (kc & 1) * 32 + 8 * g;
      float s[8];
      {
        bf16x8 r0 = *(const bf16x8*)(R0 + base);
        #pragma unroll
        for (int e = 0; e < 8; ++e) s[e] = (float)r0[e];
      }
      #pragma unroll
      for (int js = 1; js < JS; ++js) {
        bf16x8 rr = *(const bf16x8*)(Rlin + (size_t)(js - 1) * RPE + base);
        #pragma unroll
        for (int e = 0; e < 8; ++e) s[e] += (float)rr[e];
      }
      const float iv = invd[n][h];
      #pragma unroll
      for (int e = 0; e < 8; ++e) bx[n][e] = (bf16)(s[e] * iv);
    }
    #pragma unroll
    for (int m = 0; m < 4; ++m)
      #pragma unroll
      for (int n = 0; n < 2; ++n) acc[m][n] = MFMA16(aw[m], bx[n], acc[m][n]);
  }

  #pragma unroll
  for (int m = 0; m < 4; ++m)
    #pragma unroll
    for (int r = 0; r < 4; ++r) {
      const int o = o0 + 16 * m + 4 * g + r;
      const float bias = bm[o];
      #pragma unroll
      for (int n = 0; n < 2; ++n) {
        const int l = l0 + 16 * n + lo;
        size_t idx = ((size_t)b * CH + o) * (size_t)L + l;
        out[idx] = acc[m][n][r] + bias + x[idx];
      }
    }
}

// ---------------- launcher ----------------
extern "C" void kernel_launch(void* const* d_in, const int* in_sizes, int n_in,
                              void* d_out, int out_size, void* d_ws, size_t ws_size,
                              hipStream_t stream) {
  const float* x  = (const float*)d_in[0];
  const float* Wq = (const float*)d_in[1];
  const float* bq = (const float*)d_in[2];
  const float* Wk = (const float*)d_in[3];
  const float* bk = (const float*)d_in[4];
  const float* Wv = (const float*)d_in[5];
  const float* bv = (const float*)d_in[6];
  const float* Wm = (const float*)d_in[7];
  const float* bm = (const float*)d_in[8];
  float* out = (float*)d_out;

  char* ws = (char*)d_ws;
  bf16*  Wall = (bf16*)(ws + OFF_WALL);
  bf16*  Wmb  = (bf16*)(ws + OFF_WMB);
  float* ball = (float*)(ws + OFF_BALL);
  bf16*  xT   = (bf16*)(ws + OFF_XT);
  bf16*  Qt   = (bf16*)(ws + OFF_QT);
  bf16*  Kt   = (bf16*)(ws + OFF_KT);
  bf16*  Vd   = (bf16*)(ws + OFF_VD);

  bf16* Rp0  = (bf16*)(ws + OFF_XT);   // aliases xT (dead after k_proj)
  bf16* Rlin = (bf16*)(ws + OFF_RP1);

  k_prep<<<2305, 256, 0, stream>>>(Wq, Wk, Wv, bq, bk, bv, Wm, x, Wall, ball, Wmb, xT);
  k_proj<<<dim3(32, 12, 2), 256, 0, stream>>>(Wall, ball, xT, Qt, Kt, Vd);

  if (ws_size >= NEED4) {
    float* Dp = (float*)(ws + OFF_DP4);
    k_attn<4><<<512, 256, 0, stream>>>(Qt, Kt, Vd, Rp0, Rlin, Dp);
    k_out<4><<<dim3(128, 2), 256, 0, stream>>>(Wmb, Rp0, Rlin, Dp, x, bm, out);
  } else {
    float* Dp = (float*)(ws + OFF_DP2);
    k_attn<2><<<256, 256, 0, stream>>>(Qt, Kt, Vd, Rp0, Rlin, Dp);
    k_out<2><<<dim3(128, 2), 256, 0, stream>>>(Wmb, Rp0, Rlin, Dp, x, bm, out);
  }
}

// Round 12
// 91.062 us; speedup vs baseline: 1.2219x; 1.2219x over previous
//
#include <hip/hip_runtime.h>
#include <hip/hip_bf16.h>
#include <cstdint>
#include <cstddef>

typedef __bf16 bf16;
typedef bf16 bf16x8 __attribute__((ext_vector_type(8)));
typedef bf16 bf16x4 __attribute__((ext_vector_type(4)));
typedef bf16 bf16x2 __attribute__((ext_vector_type(2)));
typedef float f32x4 __attribute__((ext_vector_type(4)));
typedef float f32x16 __attribute__((ext_vector_type(16)));

#define MFMA16(A, B, Cc) __builtin_amdgcn_mfma_f32_16x16x32_bf16((A), (B), (Cc), 0, 0, 0)
#define MFMA32(A, B, Cc) __builtin_amdgcn_mfma_f32_32x32x16_bf16((A), (B), (Cc), 0, 0, 0)
#define GLD16(g, l)                                                          \
  __builtin_amdgcn_global_load_lds(                                          \
      (const __attribute__((address_space(1))) void*)(g),                    \
      (__attribute__((address_space(3))) void*)(l), 16, 0, 0)

static constexpr int L   = 4096;  // H*W
static constexpr int CH  = 256;   // channels
static constexpr int NH  = 4;     // heads

// workspace layout (bytes), all 16B aligned
static constexpr size_t OFF_WALL = 0;         // 768*256 bf16
static constexpr size_t OFF_WMB  = 393216;    // 256*256 bf16
static constexpr size_t OFF_BALL = 524288;    // 768 f32 (+pad)
static constexpr size_t OFF_XT   = 528384;    // [B][L][C] bf16 (4MB) -- Rp0 aliases after k_proj
static constexpr size_t OFF_QT   = 4722688;   // [B][H][L][64] bf16 (4MB)
static constexpr size_t OFF_KT   = 8916992;   // [B][H][L][64] bf16 (4MB)
static constexpr size_t OFF_VD   = 13111296;  // [B][H][64][L] bf16 (4MB, j-bits-2/3-swapped)
static constexpr size_t OFF_RP1  = 17305600;  // partial R js=1 (4MB)
static constexpr size_t OFF_RP2  = 21499904;  // partial R js=2 (4MB)
static constexpr size_t OFF_RP3  = 25694208;  // partial R js=3 (4MB)
static constexpr size_t OFF_DP4  = 29888512;  // 4 x [8][4096] f32 denoms (512KB)
static constexpr size_t OFF_DP2  = 21499904;  // JS=2: denoms after RP1
static constexpr size_t NEED4    = 30412800;

// ---------------- kernel 0: weight/bias convert + x transpose (merged) -------
__global__ __launch_bounds__(256) void k_prep(
    const float* __restrict__ Wq, const float* __restrict__ Wk,
    const float* __restrict__ Wv, const float* __restrict__ bq,
    const float* __restrict__ bk, const float* __restrict__ bv,
    const float* __restrict__ Wm, const float* __restrict__ x,
    bf16* __restrict__ Wall, float* __restrict__ ball,
    bf16* __restrict__ Wmb, bf16* __restrict__ xT) {
  __shared__ float t[32][33];
  const int bid = blockIdx.x;
  const int tid = threadIdx.x;
  if (bid < 1027) {
    int id = bid * 256 + tid;
    if (id < 65536)        Wall[id] = (bf16)Wq[id];
    else if (id < 131072)  Wall[id] = (bf16)Wk[id - 65536];
    else if (id < 196608)  Wall[id] = (bf16)Wv[id - 131072];
    else if (id < 262144)  Wmb[id - 196608] = (bf16)Wm[id - 196608];
    else if (id < 262912) {
      int k = id - 262144;
      ball[k] = (k < 256) ? bq[k] : (k < 512) ? bk[k - 256] : bv[k - 512];
    }
  } else {
    const int id = bid - 1027;          // 0..2047
    const int b = id >> 10;
    const int c0 = ((id >> 7) & 7) * 32;
    const int l0 = (id & 127) * 32;
    const int tx = tid & 31, ty = tid >> 5;
    #pragma unroll
    for (int i = 0; i < 4; ++i) {
      int c = c0 + ty + 8 * i;
      t[ty + 8 * i][tx] = x[((size_t)b * CH + c) * L + l0 + tx];
    }
    __syncthreads();
    #pragma unroll
    for (int i = 0; i < 4; ++i) {
      int l = l0 + ty + 8 * i;
      xT[((size_t)b * L + l) * CH + c0 + tx] = (bf16)t[tx][ty + 8 * i];
    }
  }
}

// ---------------- kernel 2: fused QKV projection + L2 norm ----------------
// V stored with j-bits 2<->3 swapped along L (so k_attn's PV A-frag is a
// straight register pack of the QK output -- see k_attn).
__global__ __launch_bounds__(256) void k_proj(
    const bf16* __restrict__ Wall, const float* __restrict__ ball,
    const bf16* __restrict__ xT, bf16* __restrict__ Qt,
    bf16* __restrict__ Kt, bf16* __restrict__ Vd) {
  const int b = blockIdx.z, strip = blockIdx.y, lt = blockIdx.x;
  const int w = threadIdx.x >> 6;
  const int lane = threadIdx.x & 63;
  const int lo = lane & 15, g = lane >> 4;
  const int l0 = lt * 256 + w * 64;

  const bf16* wbase = Wall + (size_t)strip * 64 * CH;
  const bf16* xbase = xT + (size_t)b * L * CH;

  f32x4 acc[4][4];
  #pragma unroll
  for (int m = 0; m < 4; ++m)
    #pragma unroll
    for (int n = 0; n < 4; ++n) acc[m][n] = (f32x4){0.f, 0.f, 0.f, 0.f};

  #pragma unroll
  for (int kc = 0; kc < 8; ++kc) {
    bf16x8 aw[4], bx[4];
    #pragma unroll
    for (int m = 0; m < 4; ++m)
      aw[m] = *(const bf16x8*)(wbase + (size_t)(16 * m + lo) * CH + kc * 32 + g * 8);
    #pragma unroll
    for (int n = 0; n < 4; ++n)
      bx[n] = *(const bf16x8*)(xbase + (size_t)(l0 + 16 * n + lo) * CH + kc * 32 + g * 8);
    #pragma unroll
    for (int m = 0; m < 4; ++m)
      #pragma unroll
      for (int n = 0; n < 4; ++n) acc[m][n] = MFMA16(aw[m], bx[n], acc[m][n]);
  }

  #pragma unroll
  for (int m = 0; m < 4; ++m)
    #pragma unroll
    for (int r = 0; r < 4; ++r) {
      float bias = ball[strip * 64 + 16 * m + 4 * g + r];
      #pragma unroll
      for (int n = 0; n < 4; ++n) acc[m][n][r] += bias;
    }

  if (strip < 8) {
    #pragma unroll
    for (int n = 0; n < 4; ++n) {
      float ss = 0.f;
      #pragma unroll
      for (int m = 0; m < 4; ++m)
        #pragma unroll
        for (int r = 0; r < 4; ++r) ss += acc[m][n][r] * acc[m][n][r];
      ss += __shfl_xor(ss, 16);
      ss += __shfl_xor(ss, 32);
      float sc = 1.f / fmaxf(sqrtf(ss), 1e-6f);
      #pragma unroll
      for (int m = 0; m < 4; ++m)
        #pragma unroll
        for (int r = 0; r < 4; ++r) acc[m][n][r] *= sc;
    }
    bf16* dst = (strip < 4) ? Qt : Kt;
    const int h = strip & 3;
    #pragma unroll
    for (int n = 0; n < 4; ++n) {
      const int l = l0 + 16 * n + lo;
      #pragma unroll
      for (int m = 0; m < 4; ++m) {
        size_t base = ((size_t)(b * NH + h) * L + l) * 64 + 16 * m + 4 * g;
        bf16x2 v01, v23;
        v01[0] = (bf16)acc[m][n][0]; v01[1] = (bf16)acc[m][n][1];
        v23[0] = (bf16)acc[m][n][2]; v23[1] = (bf16)acc[m][n][3];
        *(bf16x2*)(dst + base)     = v01;
        *(bf16x2*)(dst + base + 2) = v23;
      }
    }
  } else {
    const int h = strip - 8;
    const int lop = (lo & 3) | ((lo & 4) << 1) | ((lo & 8) >> 1);  // swap bits 2,3
    #pragma unroll
    for (int m = 0; m < 4; ++m)
      #pragma unroll
      for (int r = 0; r < 4; ++r) {
        const int d = 16 * m + 4 * g + r;
        #pragma unroll
        for (int n = 0; n < 4; ++n) {
          const int l = l0 + 16 * n + lop;
          Vd[((size_t)(b * NH + h) * 64 + d) * L + l] = (bf16)acc[m][n][r];
        }
      }
  }
}

// ---------------- kernel 3: attention (32x32 MFMA, in-register P) -----------
// 4 waves x 64 q = 256 q/block. K [j][d] and V [dv][j'] staged in LDS via
// global_load_lds (linear dest, inverse-swizzled source, swizzled ds_read).
// Swapped QK (A=K, B=Q): lane owns q-col = lane&31; 16 regs = 16 j's. V's
// j-axis is bit-2/3-swapped so PV A-frags = pack of consecutive p regs.
// j split JS ways across blocks; unnormalized bf16 partials + f32 denom.

#define STAGE(bb, j0)                                                          \
  {                                                                            \
    const char* gk0 = kbase + (size_t)((j0) + sr) * 128 + scS;                 \
    const char* gk1 = kbase + (size_t)((j0) + 32 + sr) * 128 + scS;            \
    const char* gv0 = vbase + (size_t)sr * 8192 + (size_t)(j0) * 2 + scS;      \
    const char* gv1 = vbase + (size_t)(32 + sr) * 8192 + (size_t)(j0) * 2 + scS; \
    GLD16(gk0, kbuf[bb] + tid * 16);                                           \
    GLD16(gk1, kbuf[bb] + 4096 + tid * 16);                                    \
    GLD16(gv0, vbuf[bb] + tid * 16);                                           \
    GLD16(gv1, vbuf[bb] + 4096 + tid * 16);                                    \
  }

#define COMPUTE(bb)                                                            \
  {                                                                            \
    const char* kb = kbuf[bb];                                                 \
    const char* vb = vbuf[bb];                                                 \
    _Pragma("unroll") for (int jb = 0; jb < 2; ++jb) {                         \
      bf16x8 kf[4], vf[2][2];                                                  \
      _Pragma("unroll") for (int f = 0; f < 4; ++f)                            \
        kf[f] = *(const bf16x8*)(kb + (32 * jb + ln) * 128 +                   \
                                 ((32 * f + 16 * hi) ^ sw));                   \
      _Pragma("unroll") for (int dvb = 0; dvb < 2; ++dvb)                      \
        _Pragma("unroll") for (int c = 0; c < 2; ++c)                          \
          vf[dvb][c] = *(const bf16x8*)(vb + (32 * dvb + ln) * 128 +           \
                                        ((64 * jb + 32 * c + 16 * hi) ^ sw));  \
      _Pragma("unroll") for (int qb = 0; qb < 2; ++qb) {                       \
        f32x16 z;                                                              \
        _Pragma("unroll") for (int r = 0; r < 16; ++r) z[r] = 0.f;             \
        _Pragma("unroll") for (int f = 0; f < 4; ++f)                          \
          z = MFMA32(kf[f], qf[qb][f], z);                                     \
        float p[16];                                                           \
        _Pragma("unroll") for (int r = 0; r < 16; ++r) p[r] = __expf(z[r]);    \
        float t0 = (p[0] + p[1]) + (p[2] + p[3]);                              \
        float t1 = (p[4] + p[5]) + (p[6] + p[7]);                              \
        float t2 = (p[8] + p[9]) + (p[10] + p[11]);                            \
        float t3 = (p[12] + p[13]) + (p[14] + p[15]);                          \
        den[qb] += (t0 + t1) + (t2 + t3);                                      \
        bf16x8 pf0, pf1;                                                       \
        _Pragma("unroll") for (int e = 0; e < 8; ++e) {                        \
          pf0[e] = (bf16)p[e];                                                 \
          pf1[e] = (bf16)p[8 + e];                                             \
        }                                                                      \
        _Pragma("unroll") for (int dvb = 0; dvb < 2; ++dvb) {                  \
          racc[qb][dvb] = MFMA32(pf0, vf[dvb][0], racc[qb][dvb]);              \
          racc[qb][dvb] = MFMA32(pf1, vf[dvb][1], racc[qb][dvb]);              \
        }                                                                      \
      }                                                                        \
    }                                                                          \
  }

template <int JS>
__global__ __launch_bounds__(256, 2) void k_attn(
    const bf16* __restrict__ Qt, const bf16* __restrict__ Kt,
    const bf16* __restrict__ Vd, bf16* __restrict__ R0,
    bf16* __restrict__ R1, bf16* __restrict__ R2, bf16* __restrict__ R3,
    float* __restrict__ D0, float* __restrict__ D1,
    float* __restrict__ D2, float* __restrict__ D3) {
  const int id = blockIdx.x;
  const int bh = id & 7;
  const int qt = (id >> 3) & 15;
  const int js = id >> 7;
  const int tid = threadIdx.x;
  const int w = tid >> 6;
  const int lane = tid & 63;
  const int ln = lane & 31, hi = lane >> 5;
  const int sw = (ln & 7) << 4;
  const int i0 = qt * 256 + w * 64;

  __shared__ __align__(16) char kbuf[2][8192];
  __shared__ __align__(16) char vbuf[2][8192];

  const char* kbase = (const char*)(Kt + (size_t)bh * L * 64);
  const char* vbase = (const char*)(Vd + (size_t)bh * 64 * L);

  const int sr = tid >> 3;
  const int sc = (tid & 7) * 16;
  const int scS = sc ^ ((sr & 7) << 4);

  // Q B-frags: qf[qb][f] = Q[i0+32qb+ln][16f+8hi .. +7]
  const bf16* qbp = Qt + ((size_t)bh * L + i0) * 64;
  bf16x8 qf[2][4];
  #pragma unroll
  for (int qb = 0; qb < 2; ++qb)
    #pragma unroll
    for (int f = 0; f < 4; ++f)
      qf[qb][f] = *(const bf16x8*)(qbp + (size_t)(32 * qb + ln) * 64 + 16 * f + 8 * hi);

  f32x16 racc[2][2];
  #pragma unroll
  for (int qb = 0; qb < 2; ++qb)
    #pragma unroll
    for (int dvb = 0; dvb < 2; ++dvb)
      #pragma unroll
      for (int r = 0; r < 16; ++r) racc[qb][dvb][r] = 0.f;
  float den[2] = {0.f, 0.f};

  const int jbeg = js * (L / JS);
  const int nt = (L / JS) / 64;

  STAGE(0, jbeg)
  __syncthreads();
  for (int it = 0; it < nt; ++it) {
    const int bb = it & 1;
    if (it + 1 < nt) STAGE(bb ^ 1, jbeg + (it + 1) * 64)
    COMPUTE(bb)
    __syncthreads();  // drains stage vmcnt + guards buffer reuse
  }

  // full denominator: lane-local sum covers its hi-half of j; add the other.
  #pragma unroll
  for (int qb = 0; qb < 2; ++qb) den[qb] += __shfl_xor(den[qb], 32);

  bf16* rp = (js == 0) ? R0 : (js == 1) ? R1 : (js == 2) ? R2 : R3;
  float* dp = (js == 0) ? D0 : (js == 1) ? D1 : (js == 2) ? D2 : D3;

  if (hi == 0) {
    #pragma unroll
    for (int qb = 0; qb < 2; ++qb)
      dp[(size_t)bh * L + i0 + 32 * qb + ln] = den[qb];
  }
  #pragma unroll
  for (int qb = 0; qb < 2; ++qb)
    #pragma unroll
    for (int dvb = 0; dvb < 2; ++dvb)
      #pragma unroll
      for (int r = 0; r < 16; ++r) {
        const int q = 32 * qb + (r & 3) + 8 * (r >> 2) + 4 * hi;
        rp[((size_t)bh * L + i0 + q) * 64 + 32 * dvb + ln] = (bf16)racc[qb][dvb][r];
      }
}

// ---------------- kernel 4: output projection + combine + bias + residual ----
// B-frags built on the fly from the JS unnormalized partials + denominators.
template <int JS>
__global__ __launch_bounds__(256) void k_out(
    const bf16* __restrict__ Wmb, const bf16* __restrict__ R0,
    const bf16* __restrict__ R1, const bf16* __restrict__ R2,
    const bf16* __restrict__ R3, const float* __restrict__ D0,
    const float* __restrict__ D1, const float* __restrict__ D2,
    const float* __restrict__ D3, const float* __restrict__ x,
    const float* __restrict__ bm, float* __restrict__ out) {
  const int b = blockIdx.y, lt = blockIdx.x;  // 128 l-tiles of 32
  const int w = threadIdx.x >> 6;
  const int lane = threadIdx.x & 63;
  const int lo = lane & 15, g = lane >> 4;
  const int o0 = w * 64, l0 = lt * 32;

  float invd[2][4];
  #pragma unroll
  for (int n = 0; n < 2; ++n) {
    const int l = l0 + 16 * n + lo;
    #pragma unroll
    for (int h = 0; h < 4; ++h) {
      const size_t di = (size_t)(b * NH + h) * L + l;
      float dd = D0[di] + D1[di];
      if (JS == 4) dd += D2[di] + D3[di];
      invd[n][h] = 1.0f / dd;
    }
  }

  f32x4 acc[4][2];
  #pragma unroll
  for (int m = 0; m < 4; ++m)
    #pragma unroll
    for (int n = 0; n < 2; ++n) acc[m][n] = (f32x4){0.f, 0.f, 0.f, 0.f};

  #pragma unroll
  for (int kc = 0; kc < 8; ++kc) {
    bf16x8 aw[4], bx[2];
    #pragma unroll
    for (int m = 0; m < 4; ++m)
      aw[m] = *(const bf16x8*)(Wmb + (size_t)(o0 + 16 * m + lo) * CH + kc * 32 + g * 8);
    const int h = kc >> 1;
    #pragma unroll
    for (int n = 0; n < 2; ++n) {
      const size_t base = ((size_t)(b * NH + h) * L + (l0 + 16 * n + lo)) * 64 +
                          (kc & 1) * 32 + 8 * g;
      bf16x8 r0 = *(const bf16x8*)(R0 + base);
      bf16x8 r1 = *(const bf16x8*)(R1 + base);
      const float iv = invd[n][h];
      if (JS == 4) {
        bf16x8 r2 = *(const bf16x8*)(R2 + base);
        bf16x8 r3 = *(const bf16x8*)(R3 + base);
        #pragma unroll
        for (int e = 0; e < 8; ++e) {
          float s = ((float)r0[e] + (float)r1[e]) + ((float)r2[e] + (float)r3[e]);
          bx[n][e] = (bf16)(s * iv);
        }
      } else {
        #pragma unroll
        for (int e = 0; e < 8; ++e)
          bx[n][e] = (bf16)(((float)r0[e] + (float)r1[e]) * iv);
      }
    }
    #pragma unroll
    for (int m = 0; m < 4; ++m)
      #pragma unroll
      for (int n = 0; n < 2; ++n) acc[m][n] = MFMA16(aw[m], bx[n], acc[m][n]);
  }

  #pragma unroll
  for (int m = 0; m < 4; ++m)
    #pragma unroll
    for (int r = 0; r < 4; ++r) {
      const int o = o0 + 16 * m + 4 * g + r;
      const float bias = bm[o];
      #pragma unroll
      for (int n = 0; n < 2; ++n) {
        const int l = l0 + 16 * n + lo;
        size_t idx = ((size_t)b * CH + o) * (size_t)L + l;
        out[idx] = acc[m][n][r] + bias + x[idx];
      }
    }
}

// ---------------- launcher ----------------
extern "C" void kernel_launch(void* const* d_in, const int* in_sizes, int n_in,
                              void* d_out, int out_size, void* d_ws, size_t ws_size,
                              hipStream_t stream) {
  const float* x  = (const float*)d_in[0];
  const float* Wq = (const float*)d_in[1];
  const float* bq = (const float*)d_in[2];
  const float* Wk = (const float*)d_in[3];
  const float* bk = (const float*)d_in[4];
  const float* Wv = (const float*)d_in[5];
  const float* bv = (const float*)d_in[6];
  const float* Wm = (const float*)d_in[7];
  const float* bm = (const float*)d_in[8];
  float* out = (float*)d_out;

  char* ws = (char*)d_ws;
  bf16*  Wall = (bf16*)(ws + OFF_WALL);
  bf16*  Wmb  = (bf16*)(ws + OFF_WMB);
  float* ball = (float*)(ws + OFF_BALL);
  bf16*  xT   = (bf16*)(ws + OFF_XT);
  bf16*  Qt   = (bf16*)(ws + OFF_QT);
  bf16*  Kt   = (bf16*)(ws + OFF_KT);
  bf16*  Vd   = (bf16*)(ws + OFF_VD);

  bf16* Rp0 = (bf16*)(ws + OFF_XT);   // aliases xT (dead after k_proj)
  bf16* Rp1 = (bf16*)(ws + OFF_RP1);

  k_prep<<<3075, 256, 0, stream>>>(Wq, Wk, Wv, bq, bk, bv, Wm, x, Wall, ball, Wmb, xT);
  k_proj<<<dim3(16, 12, 2), 256, 0, stream>>>(Wall, ball, xT, Qt, Kt, Vd);

  if (ws_size >= NEED4) {
    bf16*  Rp2 = (bf16*)(ws + OFF_RP2);
    bf16*  Rp3 = (bf16*)(ws + OFF_RP3);
    float* Dp  = (float*)(ws + OFF_DP4);
    float* D0 = Dp, *D1 = Dp + 32768, *D2 = Dp + 65536, *D3 = Dp + 98304;
    k_attn<4><<<512, 256, 0, stream>>>(Qt, Kt, Vd, Rp0, Rp1, Rp2, Rp3, D0, D1, D2, D3);
    k_out<4><<<dim3(128, 2), 256, 0, stream>>>(Wmb, Rp0, Rp1, Rp2, Rp3, D0, D1, D2, D3,
                                               x, bm, out);
  } else {
    float* Dp = (float*)(ws + OFF_DP2);
    float* D0 = Dp, *D1 = Dp + 32768;
    k_attn<2><<<256, 256, 0, stream>>>(Qt, Kt, Vd, Rp0, Rp1, nullptr, nullptr,
                                       D0, D1, nullptr, nullptr);
    k_out<2><<<dim3(128, 2), 256, 0, stream>>>(Wmb, Rp0, Rp1, nullptr, nullptr,
                                               D0, D1, nullptr, nullptr, x, bm, out);
  }
}